// Round 1
// baseline (472.388 us; speedup 1.0000x reference)
//
#include <hip/hip_runtime.h>

typedef float  f32x4  __attribute__((ext_vector_type(4)));
typedef __bf16 bf16x8 __attribute__((ext_vector_type(8)));

#define LOG2E      1.4426950408889634f
#define TWO_LOG2E  2.8853900817779268f

__device__ __forceinline__ float fast_tanh(float x) {
    // tanh(x) = 1 - 2/(e^{2x}+1); exp2-based, graceful at +/-inf
    float e = __builtin_amdgcn_exp2f(x * TWO_LOG2E);
    return 1.0f - 2.0f * __builtin_amdgcn_rcpf(e + 1.0f);
}

// ---------------------------------------------------------------------------
// K1a: convert W_h (512x512 fp32, [o][h]) to bf16, pre-swizzled into MFMA
// B-fragment order. Chunk (16B = 8 bf16 along k) index:
//   ((nc*16 + s)*16 + w*4 + nt)*64 + (q*16 + lm)
// where n = nc*256 + w*64 + nt*16 + lm, k8 = s*4 + q  (k = k8*8 + j).
// ---------------------------------------------------------------------------
__global__ void wh_swizzle_kernel(const float* __restrict__ Wh,
                                  __bf16* __restrict__ Wswz) {
    int gid = blockIdx.x * 256 + threadIdx.x;      // 0..32767
    int n   = gid >> 6;
    int k8  = gid & 63;
    const float* g = Wh + ((long)n << 9) + (k8 << 3);
    f32x4 f0 = *(const f32x4*)g;
    f32x4 f1 = *(const f32x4*)(g + 4);
    bf16x8 val;
    val[0] = (__bf16)f0[0]; val[1] = (__bf16)f0[1];
    val[2] = (__bf16)f0[2]; val[3] = (__bf16)f0[3];
    val[4] = (__bf16)f1[0]; val[5] = (__bf16)f1[1];
    val[6] = (__bf16)f1[2]; val[7] = (__bf16)f1[3];
    int nc = n >> 8, w = (n >> 6) & 3, nt = (n >> 4) & 3, lm = n & 15;
    int s  = k8 >> 2, q = k8 & 3;
    long chunk = (long)(((nc * 16 + s) * 16 + w * 4 + nt) * 64 + (q * 16 + lm));
    *(bf16x8*)(Wswz + (chunk << 3)) = val;
}

// ---------------------------------------------------------------------------
// K1b: q_proj[b][o] = sum_h query[b][h] * W_q[o][h]   (fp32, exact)
// ---------------------------------------------------------------------------
__global__ void qproj_kernel(const float* __restrict__ query,
                             const float* __restrict__ Wq,
                             float* __restrict__ qp) {
    int b = blockIdx.x >> 1;
    int o = ((blockIdx.x & 1) << 8) + threadIdx.x;
    const f32x4* qrow = (const f32x4*)(query + (b << 9));
    const f32x4* wrow = (const f32x4*)(Wq + ((long)o << 9));
    float acc = 0.f;
    #pragma unroll 4
    for (int i = 0; i < 128; ++i) {
        f32x4 a = qrow[i], w = wrow[i];
        acc += a[0]*w[0] + a[1]*w[1] + a[2]*w[2] + a[3]*w[3];
    }
    qp[(b << 9) + o] = acc;
}

// ---------------------------------------------------------------------------
// K2: fused scores + exp + context-partial. One block = 64 rows of (b,s).
//  - enc rows staged fp32->bf16 into LDS once (XOR-swizzled chunk layout)
//  - MFMA 16x16x32 bf16, acc initialized with q_proj (so acc = h_proj+q_proj)
//  - epilogue: score = sum_n v[n]*tanh(acc); e = exp(score) -> alpha region
//  - context partial: sum_m e_m * enc[m][h] from resident LDS tile
// ---------------------------------------------------------------------------
__global__ __launch_bounds__(256, 2) void score_ctx_kernel(
    const float*  __restrict__ enc,
    const __bf16* __restrict__ Wswz,
    const float*  __restrict__ qp,
    const float*  __restrict__ v,
    float* __restrict__ alpha_out,   // (B*S) unnormalized e^score
    float* __restrict__ ctx_acc,     // (B*H) atomic accumulation
    float* __restrict__ denom)       // (B)   atomic accumulation
{
    __shared__ __align__(16) unsigned char ldsA[65536]; // 64 rows x 512 k bf16, swizzled
    __shared__ float score_lds[256];                    // [wave][64 rows]
    __shared__ float escore[64];

    const int  t    = threadIdx.x;
    const int  w    = t >> 6;        // wave id (N-slice owner)
    const int  l    = t & 63;        // lane
    const long row0 = (long)blockIdx.x << 6;
    const int  b    = (int)(row0 >> 13);

    // ---- stage A: enc[row0..row0+63][0..511] fp32 -> bf16 swizzled ----
    #pragma unroll
    for (int i = 0; i < 16; ++i) {
        int cflat = t + (i << 8);
        int m = cflat >> 6, k8 = cflat & 63;
        const float* g = enc + ((row0 + m) << 9) + (k8 << 3);
        f32x4 f0 = *(const f32x4*)g;
        f32x4 f1 = *(const f32x4*)(g + 4);
        bf16x8 val;
        val[0] = (__bf16)f0[0]; val[1] = (__bf16)f0[1];
        val[2] = (__bf16)f0[2]; val[3] = (__bf16)f0[3];
        val[4] = (__bf16)f1[0]; val[5] = (__bf16)f1[1];
        val[6] = (__bf16)f1[2]; val[7] = (__bf16)f1[3];
        int chunk = ((m >> 4) * 16 + (k8 >> 2)) * 64 +
                    ((((k8 & 3) << 4) | (m & 15)) ^ ((k8 >> 2) & 7));
        *(bf16x8*)(ldsA + (chunk << 4)) = val;
    }

    // ---- acc init = q_proj[b][n] (fold the bias into the MFMA C operand) ----
    f32x4 acc[2][4][4];     // [nc][nt][mt]
    float vv[2][4];
    #pragma unroll
    for (int nc = 0; nc < 2; ++nc)
        #pragma unroll
        for (int nt = 0; nt < 4; ++nt) {
            int n = (nc << 8) + (w << 6) + (nt << 4) + (l & 15);
            float q = qp[(b << 9) + n];
            vv[nc][nt] = v[n];
            f32x4 qv = {q, q, q, q};
            #pragma unroll
            for (int mt = 0; mt < 4; ++mt) acc[nc][nt][mt] = qv;
        }

    __syncthreads();

    // ---- barrier-free K-loop: A frags from LDS, B frags straight from L2 ----
    const bf16x8* Bg = (const bf16x8*)Wswz;
    #pragma unroll 2
    for (int s = 0; s < 16; ++s) {
        bf16x8 af[4];
        #pragma unroll
        for (int mt = 0; mt < 4; ++mt)
            af[mt] = *(const bf16x8*)(ldsA + (((((mt << 4) + s) << 6) + (l ^ (s & 7))) << 4));
        #pragma unroll
        for (int nc = 0; nc < 2; ++nc)
            #pragma unroll
            for (int nt = 0; nt < 4; ++nt) {
                bf16x8 bf = Bg[(long)((((nc << 4) + s) << 4) + (w << 2) + nt) * 64 + l];
                #pragma unroll
                for (int mt = 0; mt < 4; ++mt)
                    acc[nc][nt][mt] = __builtin_amdgcn_mfma_f32_16x16x32_bf16(
                        af[mt], bf, acc[nc][nt][mt], 0, 0, 0);
            }
    }

    // ---- epilogue: per-row score partials over this wave's N-slice ----
    float srow[16];
    #pragma unroll
    for (int i = 0; i < 16; ++i) srow[i] = 0.f;
    #pragma unroll
    for (int nc = 0; nc < 2; ++nc)
        #pragma unroll
        for (int nt = 0; nt < 4; ++nt) {
            float vn = vv[nc][nt];
            #pragma unroll
            for (int mt = 0; mt < 4; ++mt)
                #pragma unroll
                for (int r = 0; r < 4; ++r)
                    srow[mt * 4 + r] += vn * fast_tanh(acc[nc][nt][mt][r]);
        }
    // reduce over the 16 columns held by lanes sharing (l>>4)
    #pragma unroll
    for (int i = 0; i < 16; ++i) {
        #pragma unroll
        for (int off = 1; off < 16; off <<= 1)
            srow[i] += __shfl_xor(srow[i], off, 64);
    }
    __syncthreads();   // (protects nothing in LDS yet, but orders score_lds reuse)
    if ((l & 15) == 0) {
        int qd = l >> 4;
        #pragma unroll
        for (int mt = 0; mt < 4; ++mt)
            #pragma unroll
            for (int r = 0; r < 4; ++r)
                score_lds[(w << 6) + (mt << 4) + (qd << 2) + r] = srow[mt * 4 + r];
    }
    __syncthreads();

    if (t < 64) {   // wave 0: combine 4 wave-slices, exp, write alpha, denom
        float sc = score_lds[t] + score_lds[64 + t] + score_lds[128 + t] + score_lds[192 + t];
        float e  = __builtin_amdgcn_exp2f(sc * LOG2E);
        alpha_out[row0 + t] = e;
        escore[t] = e;
        float ssum = e;
        #pragma unroll
        for (int off = 1; off < 64; off <<= 1) ssum += __shfl_xor(ssum, off, 64);
        if (t == 0) atomicAdd(denom + b, ssum);
    }
    __syncthreads();

    // ---- context partial from resident LDS tile ----
    int rg = t >> 6, k8 = t & 63;      // thread owns h-octet k8 over 16 rows
    float ca[8];
    #pragma unroll
    for (int j = 0; j < 8; ++j) ca[j] = 0.f;
    #pragma unroll
    for (int ii = 0; ii < 16; ++ii) {
        int m = (rg << 4) + ii;
        float em = escore[m];
        int chunk = ((m >> 4) * 16 + (k8 >> 2)) * 64 +
                    ((((k8 & 3) << 4) | (m & 15)) ^ ((k8 >> 2) & 7));
        bf16x8 av = *(const bf16x8*)(ldsA + (chunk << 4));
        #pragma unroll
        for (int j = 0; j < 8; ++j) ca[j] += em * (float)av[j];
    }
    __syncthreads();                    // all A reads done -> reuse region
    float* part = (float*)ldsA;         // stride 9 to dodge bank conflicts
    #pragma unroll
    for (int j = 0; j < 8; ++j) part[t * 9 + j] = ca[j];
    __syncthreads();
    for (int h = t; h < 512; h += 256) {
        int k8h = h >> 3, j = h & 7;
        float sum = 0.f;
        #pragma unroll
        for (int r2 = 0; r2 < 4; ++r2) sum += part[((r2 << 6) | k8h) * 9 + j];
        atomicAdd(ctx_acc + ((long)b << 9) + h, sum);
    }
}

// ---------------------------------------------------------------------------
// K3: normalize both outputs by denom[b]
// ---------------------------------------------------------------------------
__global__ void normalize_kernel(const float* __restrict__ ctx_acc,
                                 const float* __restrict__ denom,
                                 float* __restrict__ out) {
    int i = blockIdx.x * 256 + threadIdx.x;
    if (i < 8192) {
        int b = i >> 9;
        out[i] = ctx_acc[i] / denom[b];
    } else if (i < 8192 + 131072) {
        int b = (i - 8192) >> 13;
        out[i] = out[i] / denom[b];
    }
}

extern "C" void kernel_launch(void* const* d_in, const int* in_sizes, int n_in,
                              void* d_out, int out_size, void* d_ws, size_t ws_size,
                              hipStream_t stream) {
    const float* enc   = (const float*)d_in[0];  // (16,8192,512)
    const float* query = (const float*)d_in[1];  // (16,512)
    const float* Wh    = (const float*)d_in[2];  // (512,512)
    const float* Wq    = (const float*)d_in[3];  // (512,512)
    const float* v     = (const float*)d_in[4];  // (512,)
    float* out = (float*)d_out;                  // [context 8192 | alpha 131072]

    char* ws = (char*)d_ws;
    float*  ctx_acc = (float*)ws;                // 8192 floats  (32768 B)
    float*  denom   = (float*)(ws + 32768);      // 16 floats
    float*  qp      = (float*)(ws + 32832);      // 8192 floats  (32768 B)
    __bf16* Wswz    = (__bf16*)(ws + 65600);     // 262144 bf16  (524288 B), 16B aligned

    hipMemsetAsync(ws, 0, 32832, stream);        // zero ctx_acc + denom
    wh_swizzle_kernel<<<128, 256, 0, stream>>>(Wh, Wswz);
    qproj_kernel<<<32, 256, 0, stream>>>(query, Wq, qp);
    score_ctx_kernel<<<2048, 256, 0, stream>>>(enc, Wswz, qp, v,
                                               out + 8192, ctx_acc, denom);
    normalize_kernel<<<544, 256, 0, stream>>>(ctx_acc, denom, out);
}

// Round 2
// 424.506 us; speedup vs baseline: 1.1128x; 1.1128x over previous
//
#include <hip/hip_runtime.h>

typedef float  f32x4  __attribute__((ext_vector_type(4)));
typedef __bf16 bf16x8 __attribute__((ext_vector_type(8)));

#define LOG2E      1.4426950408889634f
#define TWO_LOG2E  2.8853900817779268f

__device__ __forceinline__ float fast_tanh(float x) {
    float e = __builtin_amdgcn_exp2f(x * TWO_LOG2E);
    return 1.0f - 2.0f * __builtin_amdgcn_rcpf(e + 1.0f);
}

// A-tile LDS swizzle: chunk(m, k8) for 16B chunk enc[m][k8*8..k8*8+7] (bf16)
//   high = (m>>4)*16 + (k8>>2)          (k8>>2 == s)
//   low6 = ((k8&3)<<4 | (m&15)) ^ ((k8>>2)&7) ^ (((k8&3)<<1)&7)
// MFMA read (lane l, tile mt, step s): low6 = l ^ (s&7) ^ (((l>>4)<<1)&7)
//   -> all 64 lanes distinct (conflict-free).
// Staging write / context read (k8 = lane, m fixed): bank-low3 =
//   (m&7) ^ ((l>>2)&7) ^ ((l&3)<<1) -> distinct within every 8-lane phase.
__device__ __forceinline__ int a_chunk(int m, int k8) {
    return (((m >> 4) * 16 + (k8 >> 2)) << 6) +
           ((((k8 & 3) << 4) | (m & 15)) ^ ((k8 >> 2) & 7) ^ (((k8 & 3) << 1) & 7));
}

// ---------------------------------------------------------------------------
// K1a: W_h (512x512 fp32 [o][h]) -> bf16 B-fragment order:
//   chunk = ((n>>4)*16 + (k8>>2))*64 + ((k8&3)<<4 | (n&15))
// K-loop read: wave w, n-tile nt, step s: Bg[(((w*4+nt)*16 + s)<<6) + lane]
// ---------------------------------------------------------------------------
__global__ void wh_swizzle_kernel(const float* __restrict__ Wh,
                                  __bf16* __restrict__ Wswz) {
    int gid = blockIdx.x * 256 + threadIdx.x;      // 0..32767
    int n   = gid >> 6;
    int k8  = gid & 63;
    const float* g = Wh + ((long)n << 9) + (k8 << 3);
    f32x4 f0 = *(const f32x4*)g;
    f32x4 f1 = *(const f32x4*)(g + 4);
    bf16x8 val;
    val[0] = (__bf16)f0[0]; val[1] = (__bf16)f0[1];
    val[2] = (__bf16)f0[2]; val[3] = (__bf16)f0[3];
    val[4] = (__bf16)f1[0]; val[5] = (__bf16)f1[1];
    val[6] = (__bf16)f1[2]; val[7] = (__bf16)f1[3];
    int chunk = (((n >> 4) * 16 + (k8 >> 2)) << 6) + (((k8 & 3) << 4) | (n & 15));
    *(bf16x8*)(Wswz + ((long)chunk << 3)) = val;
}

// ---------------------------------------------------------------------------
// K1b: q_proj[b][o] = dot(query[b], Wq[o])  — one wave per (b,o) pair,
// fully coalesced row reads + shuffle reduction.
// ---------------------------------------------------------------------------
__global__ void qproj_kernel(const float* __restrict__ query,
                             const float* __restrict__ Wq,
                             float* __restrict__ qp) {
    int pair = (blockIdx.x << 2) + (threadIdx.x >> 6);   // 0..8191 = b*512+o
    int l    = threadIdx.x & 63;
    int b    = pair >> 9;
    long o   = pair & 511;
    const f32x4* q  = (const f32x4*)(query + (b << 9) + (l << 3));
    const f32x4* wr = (const f32x4*)(Wq + (o << 9) + (l << 3));
    f32x4 a0 = q[0], a1 = q[1], w0 = wr[0], w1 = wr[1];
    float acc = a0[0]*w0[0] + a0[1]*w0[1] + a0[2]*w0[2] + a0[3]*w0[3]
              + a1[0]*w1[0] + a1[1]*w1[1] + a1[2]*w1[2] + a1[3]*w1[3];
    #pragma unroll
    for (int off = 1; off < 64; off <<= 1) acc += __shfl_xor(acc, off, 64);
    if (l == 0) qp[pair] = acc;
}

// ---------------------------------------------------------------------------
// K2: fused scores + exp + context-partial. Block = 512 threads (8 waves),
// 64 rows of (b,s). Wave w owns N-slice [w*64, w*64+64). LDS ~66 KB ->
// 2 blocks/CU = 16 waves/CU.
// ---------------------------------------------------------------------------
__global__ __launch_bounds__(512, 4) void score_ctx_kernel(
    const float*  __restrict__ enc,
    const __bf16* __restrict__ Wswz,
    const float*  __restrict__ qp,
    const float*  __restrict__ v,
    float* __restrict__ alpha_out,   // (B*S) unnormalized e^score
    float* __restrict__ ctx_acc,     // (B*H) atomic accumulation
    float* __restrict__ denom)       // (B)   atomic accumulation
{
    __shared__ __align__(16) unsigned char ldsA[65536]; // 64 rows x 512 k bf16, swizzled
    __shared__ float score_lds[512];                    // [wave][64 rows]
    __shared__ float escore[64];

    const int  t    = threadIdx.x;
    const int  w    = t >> 6;        // wave id = N-slice owner
    const int  l    = t & 63;
    const long row0 = (long)blockIdx.x << 6;
    const int  b    = (int)(row0 >> 13);

    // ---- acc init = q_proj[b][n]; v fragment ----
    f32x4 acc[4][4];     // [nt][mt]
    float vv[4];
    #pragma unroll
    for (int nt = 0; nt < 4; ++nt) {
        int n = (w << 6) + (nt << 4) + (l & 15);
        float q = qp[(b << 9) + n];
        vv[nt] = v[n];
        f32x4 qv = {q, q, q, q};
        #pragma unroll
        for (int mt = 0; mt < 4; ++mt) acc[nt][mt] = qv;
    }

    // ---- stage A: enc rows fp32 -> bf16 swizzled (8 chunks/thread) ----
    #pragma unroll
    for (int i = 0; i < 8; ++i) {
        int cflat = t + (i << 9);
        int m = cflat >> 6, k8 = cflat & 63;   // per wave: m fixed, k8 = lane
        const float* g = enc + ((row0 + m) << 9) + (k8 << 3);
        f32x4 f0 = *(const f32x4*)g;
        f32x4 f1 = *(const f32x4*)(g + 4);
        bf16x8 val;
        val[0] = (__bf16)f0[0]; val[1] = (__bf16)f0[1];
        val[2] = (__bf16)f0[2]; val[3] = (__bf16)f0[3];
        val[4] = (__bf16)f1[0]; val[5] = (__bf16)f1[1];
        val[6] = (__bf16)f1[2]; val[7] = (__bf16)f1[3];
        *(bf16x8*)(ldsA + (a_chunk(m, k8) << 4)) = val;
    }

    __syncthreads();

    // ---- barrier-free K-loop: A from LDS, B straight from L2 ----
    const bf16x8* Bg = (const bf16x8*)Wswz;
    #pragma unroll 2
    for (int s = 0; s < 16; ++s) {
        bf16x8 af[4];
        int lowr = l ^ (s & 7) ^ (((l >> 4) << 1) & 7);
        #pragma unroll
        for (int mt = 0; mt < 4; ++mt)
            af[mt] = *(const bf16x8*)(ldsA + (((((mt << 4) + s) << 6) + lowr) << 4));
        #pragma unroll
        for (int nt = 0; nt < 4; ++nt) {
            bf16x8 bf = Bg[((((w << 2) + nt) * 16 + s) << 6) + l];
            #pragma unroll
            for (int mt = 0; mt < 4; ++mt)
                acc[nt][mt] = __builtin_amdgcn_mfma_f32_16x16x32_bf16(
                    af[mt], bf, acc[nt][mt], 0, 0, 0);
        }
    }

    // ---- epilogue: per-row score partials over this wave's 64-col slice ----
    float srow[16];
    #pragma unroll
    for (int i = 0; i < 16; ++i) srow[i] = 0.f;
    #pragma unroll
    for (int nt = 0; nt < 4; ++nt) {
        float vn = vv[nt];
        #pragma unroll
        for (int mt = 0; mt < 4; ++mt)
            #pragma unroll
            for (int r = 0; r < 4; ++r)
                srow[mt * 4 + r] += vn * fast_tanh(acc[nt][mt][r]);
    }
    #pragma unroll
    for (int i = 0; i < 16; ++i) {
        #pragma unroll
        for (int off = 1; off < 16; off <<= 1)
            srow[i] += __shfl_xor(srow[i], off, 64);
    }
    if ((l & 15) == 0) {
        int qd = l >> 4;
        #pragma unroll
        for (int mt = 0; mt < 4; ++mt)
            #pragma unroll
            for (int r = 0; r < 4; ++r)
                score_lds[(w << 6) + (mt << 4) + (qd << 2) + r] = srow[mt * 4 + r];
    }
    __syncthreads();

    if (t < 64) {   // wave 0: combine 8 wave-slices, exp, alpha, denom
        float sc = 0.f;
        #pragma unroll
        for (int ww = 0; ww < 8; ++ww) sc += score_lds[(ww << 6) + t];
        float e = __builtin_amdgcn_exp2f(sc * LOG2E);
        alpha_out[row0 + t] = e;
        escore[t] = e;
        float ssum = e;
        #pragma unroll
        for (int off = 1; off < 64; off <<= 1) ssum += __shfl_xor(ssum, off, 64);
        if (t == 0) atomicAdd(denom + b, ssum);
    }
    __syncthreads();

    // ---- context partial: wave w handles rows w*8..w*8+7, lane = h-octet ----
    float ca[8];
    #pragma unroll
    for (int j = 0; j < 8; ++j) ca[j] = 0.f;
    #pragma unroll
    for (int ii = 0; ii < 8; ++ii) {
        int m = (w << 3) + ii;
        float em = escore[m];
        bf16x8 av = *(const bf16x8*)(ldsA + (a_chunk(m, l) << 4));
        #pragma unroll
        for (int j = 0; j < 8; ++j) ca[j] += em * (float)av[j];
    }
    __syncthreads();                    // all A reads done -> reuse region
    float* part = (float*)ldsA;         // 512 threads x 8 floats, stride 9
    #pragma unroll
    for (int j = 0; j < 8; ++j) part[t * 9 + j] = ca[j];
    __syncthreads();
    {
        int h = t;                      // 512 threads = 512 h values
        int k8h = h >> 3, j = h & 7;
        float sum = 0.f;
        #pragma unroll
        for (int rg = 0; rg < 8; ++rg) sum += part[((rg << 6) | k8h) * 9 + j];
        atomicAdd(ctx_acc + ((long)b << 9) + h, sum);
    }
}

// ---------------------------------------------------------------------------
// K3: normalize both outputs by denom[b]
// ---------------------------------------------------------------------------
__global__ void normalize_kernel(const float* __restrict__ ctx_acc,
                                 const float* __restrict__ denom,
                                 float* __restrict__ out) {
    int i = blockIdx.x * 256 + threadIdx.x;
    if (i < 8192) {
        int b = i >> 9;
        out[i] = ctx_acc[i] / denom[b];
    } else if (i < 8192 + 131072) {
        int b = (i - 8192) >> 13;
        out[i] = out[i] / denom[b];
    }
}

extern "C" void kernel_launch(void* const* d_in, const int* in_sizes, int n_in,
                              void* d_out, int out_size, void* d_ws, size_t ws_size,
                              hipStream_t stream) {
    const float* enc   = (const float*)d_in[0];  // (16,8192,512)
    const float* query = (const float*)d_in[1];  // (16,512)
    const float* Wh    = (const float*)d_in[2];  // (512,512)
    const float* Wq    = (const float*)d_in[3];  // (512,512)
    const float* v     = (const float*)d_in[4];  // (512,)
    float* out = (float*)d_out;                  // [context 8192 | alpha 131072]

    char* ws = (char*)d_ws;
    float*  ctx_acc = (float*)ws;                // 8192 floats
    float*  denom   = (float*)(ws + 32768);      // 16 floats
    float*  qp      = (float*)(ws + 32832);      // 8192 floats
    __bf16* Wswz    = (__bf16*)(ws + 65600);     // 262144 bf16, 16B aligned

    hipMemsetAsync(ws, 0, 32832, stream);        // zero ctx_acc + denom
    wh_swizzle_kernel<<<128, 256, 0, stream>>>(Wh, Wswz);
    qproj_kernel<<<2048, 256, 0, stream>>>(query, Wq, qp);
    score_ctx_kernel<<<2048, 512, 0, stream>>>(enc, Wswz, qp, v,
                                               out + 8192, ctx_acc, denom);
    normalize_kernel<<<544, 256, 0, stream>>>(ctx_acc, denom, out);
}